// Round 1
// baseline (230.795 us; speedup 1.0000x reference)
//
#include <hip/hip_runtime.h>

// PositionalEncoding: out[i][j] = X[i][j] + (j even ? sin(i / 10000^(j/n))
//                                                  : cos(i / 10000^((j+1)/n)))
// m=8192, n=4096, fp32. Memory-bound: 268 MB traffic -> ~43 us floor.
//
// Strategy: float4 vectorized load/add/store. Each thread owns a quad of
// columns (j0..j0+3, j0 multiple of 4) and strides over rows, so the three
// distinct inv_freq values per quad (exponents j0/n, (j0+2)/n, (j0+4)/n —
// note columns j0+1 and j0+2 share an exponent) are computed once per thread
// via exp2f and amortized over 8 rows.

constexpr int M = 8192;
constexpr int N = 4096;
constexpr int NQ = N / 4; // 1024 float4 per row

__global__ __launch_bounds__(256) void pe_kernel(const float4* __restrict__ X,
                                                 float4* __restrict__ Y) {
    const int tid = blockIdx.x * blockDim.x + threadIdx.x;
    const int cq = tid & (NQ - 1);        // column-quad index
    const int row0 = tid >> 10;           // tid / NQ
    const int row_stride = (gridDim.x * blockDim.x) >> 10;

    const int j0 = cq * 4;
    // 10000^(-e) = exp2(-e * log2(10000))
    const float L2_10K = 13.287712379549449f;
    const float s = L2_10K / (float)N;
    const float inv0  = __builtin_exp2f(-s * (float)(j0));
    const float inv12 = __builtin_exp2f(-s * (float)(j0 + 2));
    const float inv3  = __builtin_exp2f(-s * (float)(j0 + 4));

    for (int row = row0; row < M; row += row_stride) {
        const float p = (float)row;
        const long idx = (long)row * NQ + cq;
        float4 x = X[idx];
        float4 y;
        y.x = x.x + __sinf(p * inv0);
        y.y = x.y + __cosf(p * inv12);
        y.z = x.z + __sinf(p * inv12);
        y.w = x.w + __cosf(p * inv3);
        Y[idx] = y;
    }
}

extern "C" void kernel_launch(void* const* d_in, const int* in_sizes, int n_in,
                              void* d_out, int out_size, void* d_ws, size_t ws_size,
                              hipStream_t stream) {
    const float4* X = (const float4*)d_in[0];
    float4* Y = (float4*)d_out;
    // 4096 blocks x 256 threads = 1,048,576 threads = 1024 row-quads covered
    // per sweep; each thread iterates 8 rows.
    dim3 grid(4096), block(256);
    pe_kernel<<<grid, block, 0, stream>>>(X, Y);
}

// Round 3
// 228.397 us; speedup vs baseline: 1.0105x; 1.0105x over previous
//
#include <hip/hip_runtime.h>

// PositionalEncoding: out[i][j] = X[i][j] + (j even ? sin(i / 10000^(j/n))
//                                                  : cos(i / 10000^((j+1)/n)))
// m=8192, n=4096, fp32. Memory-bound: 268 MB traffic -> ~43 us floor at
// 6.3 TB/s. R1 evidence: pe_kernel absent from rocprof top-5 (all >=80 us
// dispatches are harness fills), so kernel < 80 us; graded dur_us includes
// harness reset traffic.
//
// R3 = R2 with compile fix: nontemporal builtins need a NATIVE clang vector
// type (ext_vector_type), not HIP_vector_type<float,4>.

constexpr int M = 8192;
constexpr int N = 4096;
constexpr int NQ = N / 4;          // 1024 float4 per row
constexpr int ROW_STRIDE = 1024;   // (4096 blocks * 256 thr) / NQ
constexpr int ROWS_PER_THREAD = M / ROW_STRIDE; // 8

typedef float vfloat4 __attribute__((ext_vector_type(4)));

__global__ __launch_bounds__(256) void pe_kernel(const vfloat4* __restrict__ X,
                                                 vfloat4* __restrict__ Y) {
    const int tid = blockIdx.x * blockDim.x + threadIdx.x;
    const int cq = tid & (NQ - 1);        // column-quad index
    const int row0 = tid >> 10;

    const int j0 = cq * 4;
    // 10000^(-e) = exp2(-e * log2(10000)); columns j0+1 and j0+2 share an
    // exponent ((j+j%2) identity), so only 3 exp2 per thread.
    const float L2_10K = 13.287712379549449f;
    const float s = L2_10K / (float)N;
    const float inv0  = __builtin_exp2f(-s * (float)(j0));
    const float inv12 = __builtin_exp2f(-s * (float)(j0 + 2));
    const float inv3  = __builtin_exp2f(-s * (float)(j0 + 4));

#pragma unroll
    for (int k = 0; k < ROWS_PER_THREAD; ++k) {
        const int row = row0 + k * ROW_STRIDE;
        const float p = (float)row;
        const long idx = (long)row * NQ + cq;
        vfloat4 x = __builtin_nontemporal_load(&X[idx]);
        vfloat4 y;
        y.x = x.x + __sinf(p * inv0);
        y.y = x.y + __cosf(p * inv12);
        y.z = x.z + __sinf(p * inv12);
        y.w = x.w + __cosf(p * inv3);
        __builtin_nontemporal_store(y, &Y[idx]);
    }
}

extern "C" void kernel_launch(void* const* d_in, const int* in_sizes, int n_in,
                              void* d_out, int out_size, void* d_ws, size_t ws_size,
                              hipStream_t stream) {
    const vfloat4* X = (const vfloat4*)d_in[0];
    vfloat4* Y = (vfloat4*)d_out;
    // 4096 blocks x 256 threads = 1M threads; each thread: one column quad,
    // 8 rows (stride 1024). Full occupancy (64 waves/CU at launch).
    dim3 grid(4096), block(256);
    pe_kernel<<<grid, block, 0, stream>>>(X, Y);
}